// Round 9
// baseline (73.739 us; speedup 1.0000x reference)
//
#include <hip/hip_runtime.h>

#define GAMMA 0.1f

constexpr int MTOT = 65536;
constexpr int NTOT = 1024;
constexpr int KDIM = 64;
constexpr int BM   = 64;          // x rows per block
constexpr int BNT  = 64;          // centers per iteration
constexpr int NIT  = NTOT / BNT;  // 16 center-tiles

using frag_ab = __attribute__((ext_vector_type(8))) short;  // 8 bf16 (4 VGPRs)
using f32x4   = __attribute__((ext_vector_type(4))) float;  // 4 f32 acc

typedef __attribute__((address_space(1))) const unsigned int gu32;
typedef __attribute__((address_space(3))) unsigned int lu32;

// ---------------- workspace layout (bytes) ----------------
constexpr size_t WS_CHI = 0;                 // 1024*64*2 = 131072 (pre-swizzled)
constexpr size_t WS_CLO = 131072;            // 131072
constexpr size_t WS_CSQ = 262144;            // 1024*4
constexpr size_t WS_NEEDED = 262144 + 4096;  // 266 KB (ws proven >= 17 MB in R2)

// f32 -> bf16 round-to-nearest-even; 'back' is the rounded value as f32.
__device__ __forceinline__ ushort bf16_rne(float v, float& back) {
  unsigned u = __float_as_uint(v);
  unsigned r = (u + 0x7FFFu + ((u >> 16) & 1u)) >> 16;
  back = __uint_as_float(r << 16);
  return (ushort)r;
}

// ======== kernel 1: centers f32 -> bf16 hi/lo (pre-swizzled) + csq, into ws ========
// 8192 threads: thread c -> row = c>>3 (0..1023), 16B slot s = c&7.
__global__ __launch_bounds__(256)
void cen_convert_kernel(const float* __restrict__ centers,
                        ushort* __restrict__ hi, ushort* __restrict__ lo,
                        float* __restrict__ sq) {
  const int c = blockIdx.x * 256 + threadIdx.x;
  const int row = c >> 3;
  const int s = c & 7;
  const float4* p = reinterpret_cast<const float4*>(centers + (size_t)row * KDIM + s * 8);
  float4 v0 = p[0], v1 = p[1];
  float v[8] = {v0.x, v0.y, v0.z, v0.w, v1.x, v1.y, v1.z, v1.w};
  frag_ab hv, lv;
  float ss = 0.0f;
  #pragma unroll
  for (int i = 0; i < 8; ++i) {
    float back;
    ushort hb = bf16_rne(v[i], back);
    float b2;
    ushort lb = bf16_rne(v[i] - back, b2);
    (void)b2;
    ss += v[i] * v[i];
    hv[i] = (short)hb;
    lv[i] = (short)lb;
  }
  ss += __shfl_xor(ss, 1);
  ss += __shfl_xor(ss, 2);
  ss += __shfl_xor(ss, 4);
  if (s == 0) sq[row] = ss;
  const int slot = s ^ (row & 7);  // bake LDS bank swizzle into the ws layout
  *reinterpret_cast<frag_ab*>(hi + (size_t)row * KDIM + slot * 8) = hv;
  *reinterpret_cast<frag_ab*>(lo + (size_t)row * KDIM + slot * 8) = lv;
}

// ======== kernel 2: x-resident blocks loop over L2-resident center tiles ========
// Block owns 64 x-rows (read ONCE). 16 iterations over 64-center tiles DMA'd
// from pre-converted ws (L2-resident per XCD). A=centers, B=x (R8-verified
// orientation) -> lane-local float4 epilogue along n. One barrier/iteration.
__global__ __launch_bounds__(512, 4)
void rbf_main_kernel(const float* __restrict__ x,
                     const ushort* __restrict__ chi,
                     const ushort* __restrict__ clo,
                     const float* __restrict__ csq,
                     float* __restrict__ out) {
  __shared__ ushort sXhi[BM * KDIM];          // 8 KB (XOR-swizzled)
  __shared__ ushort sXlo[BM * KDIM];          // 8 KB
  __shared__ float  sXsq[BM];                 // 256 B
  __shared__ ushort sCen[2][2 * BNT * KDIM];  // dbuf x [hi 8KB | lo 8KB] = 32 KB

  const int tid = threadIdx.x;
  const int mb  = blockIdx.x;                 // 0..1023

  // DMA one 64-center tile (hi+lo, 16 KB) into buffer b. Linear LDS dest
  // (HW requirement); swizzle is pre-baked in ws, so frag reads are
  // conflict-free (m173 pattern, proven in R7/R8).
  auto issue_cen = [&](int nt, int b) {
    const char* sH = reinterpret_cast<const char*>(chi) + (size_t)nt * BNT * KDIM * 2;
    const char* sL = reinterpret_cast<const char*>(clo) + (size_t)nt * BNT * KDIM * 2;
    char* d = reinterpret_cast<char*>(&sCen[b][0]);
    __builtin_amdgcn_global_load_lds((gu32*)(sH + (size_t)tid * 16),
                                     (lu32*)(d + (size_t)tid * 16), 16, 0, 0);
    __builtin_amdgcn_global_load_lds((gu32*)(sL + (size_t)tid * 16),
                                     (lu32*)(d + 8192 + (size_t)tid * 16), 16, 0, 0);
  };

  issue_cen(0, 0);   // overlap with x staging below

  // ---- stage x-tile once: coalesced f32 reads -> bf16 hi/lo LDS + xsq ----
  {
    const int row = tid >> 3;       // 0..63
    const int s   = tid & 7;
    const float4* p = reinterpret_cast<const float4*>(
        x + (size_t)mb * BM * KDIM + row * KDIM + s * 8);
    float4 v0 = p[0], v1 = p[1];
    float v[8] = {v0.x, v0.y, v0.z, v0.w, v1.x, v1.y, v1.z, v1.w};
    frag_ab hv, lv;
    float ss = 0.0f;
    #pragma unroll
    for (int i = 0; i < 8; ++i) {
      float back;
      ushort hb = bf16_rne(v[i], back);
      float b2;
      ushort lb = bf16_rne(v[i] - back, b2);
      (void)b2;
      ss += v[i] * v[i];
      hv[i] = (short)hb;
      lv[i] = (short)lb;
    }
    ss += __shfl_xor(ss, 1);
    ss += __shfl_xor(ss, 2);
    ss += __shfl_xor(ss, 4);
    if (s == 0) sXsq[row] = ss;
    const int slot = s ^ (row & 7);
    *reinterpret_cast<frag_ab*>(sXhi + row * 64 + slot * 8) = hv;
    *reinterpret_cast<frag_ab*>(sXlo + row * 64 + slot * 8) = lv;
  }
  __syncthreads();   // x staged; cen tile 0 DMA drained (vmcnt in barrier)

  const int lane = tid & 63;
  const int wave = tid >> 6;        // 0..7
  const int wm = wave & 3;          // m-quarter: 16 x-rows
  const int wn = wave >> 2;         // n-half of the 64-center tile: 32 centers
  const int l = lane & 15;
  const int g = lane >> 4;          // k-group 0..3

  // ---- hoist x fragments + xsq (invariant across all 16 center-tiles) ----
  frag_ab xh[2], xl[2];
  #pragma unroll
  for (int ks = 0; ks < 2; ++ks) {
    const int row = wm * 16 + l;
    const int slot = (ks * 4 + g) ^ (l & 7);
    xh[ks] = *reinterpret_cast<const frag_ab*>(sXhi + row * 64 + slot * 8);
    xl[ks] = *reinterpret_cast<const frag_ab*>(sXlo + row * 64 + slot * 8);
  }
  const float xs = sXsq[wm * 16 + l];

  const size_t orow_base = ((size_t)mb * BM + wm * 16 + l) * (size_t)NTOT;

  // ================= center-tile loop: 16 iterations, 1 barrier each =================
  #pragma unroll 1
  for (int nt = 0; nt < NIT; ++nt) {
    const int b = nt & 1;
    if (nt + 1 < NIT) issue_cen(nt + 1, b ^ 1);   // prefetch into other buffer

    const ushort* cH = &sCen[b][0];
    const ushort* cL = &sCen[b][4096];

    // ---- MFMA: cross = ch*xh + ch*xl + cl*xh (lo*lo dropped, ~1e-6) ----
    f32x4 acc[2] = {};
    #pragma unroll
    for (int ks = 0; ks < 2; ++ks) {
      const int slot = (ks * 4 + g) ^ (l & 7);
      #pragma unroll
      for (int nf = 0; nf < 2; ++nf) {
        const int row = wn * 32 + nf * 16 + l;
        const frag_ab ch = *reinterpret_cast<const frag_ab*>(cH + row * 64 + slot * 8);
        const frag_ab cl = *reinterpret_cast<const frag_ab*>(cL + row * 64 + slot * 8);
        acc[nf] = __builtin_amdgcn_mfma_f32_16x16x32_bf16(ch, xh[ks], acc[nf], 0, 0, 0);
        acc[nf] = __builtin_amdgcn_mfma_f32_16x16x32_bf16(ch, xl[ks], acc[nf], 0, 0, 0);
        acc[nf] = __builtin_amdgcn_mfma_f32_16x16x32_bf16(cl, xh[ks], acc[nf], 0, 0, 0);
      }
    }

    // ---- epilogue: lane-local finish, float4 stores along n ----
    // Block covers cols nt*64..nt*64+63 for all 64 rows -> full 128B lines.
    const int ncol = nt * 64 + wn * 32;
    float* orow = out + orow_base + ncol;
    #pragma unroll
    for (int nf = 0; nf < 2; ++nf) {
      const float4 cs = *reinterpret_cast<const float4*>(csq + ncol + nf * 16 + g * 4);
      const f32x4 a = acc[nf];
      float4 o;
      o.x = __expf(-GAMMA * fmaxf(xs + cs.x - 2.0f * a[0], 0.0f));
      o.y = __expf(-GAMMA * fmaxf(xs + cs.y - 2.0f * a[1], 0.0f));
      o.z = __expf(-GAMMA * fmaxf(xs + cs.z - 2.0f * a[2], 0.0f));
      o.w = __expf(-GAMMA * fmaxf(xs + cs.w - 2.0f * a[3], 0.0f));
      *reinterpret_cast<float4*>(orow + nf * 16 + g * 4) = o;
    }

    __syncthreads();   // next-tile DMA drained; buffer b free for nt+2
  }
}

extern "C" void kernel_launch(void* const* d_in, const int* in_sizes, int n_in,
                              void* d_out, int out_size, void* d_ws, size_t ws_size,
                              hipStream_t stream) {
  (void)in_sizes; (void)n_in; (void)out_size; (void)ws_size;
  const float* x       = (const float*)d_in[0];
  const float* centers = (const float*)d_in[1];
  float* out = (float*)d_out;

  char* ws = (char*)d_ws;
  ushort* chi = (ushort*)(ws + WS_CHI);
  ushort* clo = (ushort*)(ws + WS_CLO);
  float*  csq = (float*)(ws + WS_CSQ);

  cen_convert_kernel<<<32, 256, 0, stream>>>(centers, chi, clo, csq);
  rbf_main_kernel<<<MTOT / BM, 512, 0, stream>>>(x, chi, clo, csq, out);
}